// Round 1
// baseline (177.465 us; speedup 1.0000x reference)
//
#include <hip/hip_runtime.h>
#include <stdint.h>

#define DM 1024
#define SEQ 2048
#define NTOK 4096
#define HD 64

typedef __bf16 bf16x8 __attribute__((ext_vector_type(8)));
typedef float f32x4 __attribute__((ext_vector_type(4)));

#if __has_builtin(__builtin_amdgcn_exp2f)
#define EXP2F(x) __builtin_amdgcn_exp2f(x)
#else
#define EXP2F(x) exp2f(x)
#endif

#if __has_builtin(__builtin_amdgcn_global_load_lds)
#define HAVE_GLL 1
#define GLL16(g, l)                                                        \
  __builtin_amdgcn_global_load_lds(                                        \
      (const __attribute__((address_space(1))) void*)(g),                  \
      (__attribute__((address_space(3))) void*)(l), 16, 0, 0)
#endif

__device__ __forceinline__ uint16_t f2bf(float f) {
  uint32_t x = __float_as_uint(f);
  return (uint16_t)((x + 0x7fffu + ((x >> 16) & 1u)) >> 16);
}

// ---------------- convert x (fp32) -> bf16 ----------------
__global__ void cvt_x_kernel(const float* __restrict__ x, uint16_t* __restrict__ xb) {
  int i = (blockIdx.x * 256 + threadIdx.x) * 4;
  float4 v = *(const float4*)&x[i];
  uint64_t pk = (uint64_t)f2bf(v.x) | ((uint64_t)f2bf(v.y) << 16) |
                ((uint64_t)f2bf(v.z) << 32) | ((uint64_t)f2bf(v.w) << 48);
  *(uint64_t*)&xb[i] = pk;
}

// ---------------- transpose W (fp32 [k][n]) -> Wt bf16 [n][k] ----------------
__global__ void twt_kernel(const float* __restrict__ W, uint16_t* __restrict__ Wt) {
  __shared__ float t[32][33];
  int tx = threadIdx.x, ty = threadIdx.y;
  int kb = blockIdx.y * 32, nb = blockIdx.x * 32;
#pragma unroll
  for (int i = 0; i < 4; i++)
    t[ty + i * 8][tx] = W[(kb + ty + i * 8) * DM + nb + tx];
  __syncthreads();
#pragma unroll
  for (int i = 0; i < 4; i++)
    Wt[(nb + ty + i * 8) * DM + kb + tx] = f2bf(t[tx][ty + i * 8]);
}

// ---------------- GEMM body: C[4096,1024] = A[4096,1024] @ Bt^T + bias ----------------
// MODE 0: out bf16, layout [bh][s][64]  (q, k)
// MODE 1: out bf16, layout [bh][d][s]   (v transposed)
// MODE 2: out fp32, layout [row][col]   (final output)
template <int MODE>
__device__ __forceinline__ void gemm_body(const uint16_t* __restrict__ A,
                                          const uint16_t* __restrict__ Bt,
                                          const float* __restrict__ bias,
                                          void* __restrict__ out, uint16_t* lds) {
  const int tid = threadIdx.x;
  const int w = tid >> 6, lane = tid & 63;
  const int wr = w >> 1, wc = w & 1;
  const int a15 = lane & 15, a4 = lane >> 4;
  const int m0 = blockIdx.y * 128, n0 = blockIdx.x * 128;
  uint16_t* lgA = lds;
  uint16_t* lgB = lds + 128 * 32;
  f32x4 zero = {0.0f, 0.0f, 0.0f, 0.0f};
  f32x4 acc[4][4];
#pragma unroll
  for (int m = 0; m < 4; m++)
#pragma unroll
    for (int n = 0; n < 4; n++) acc[m][n] = zero;

  const int ob = w * 1024 + lane * 16;  // byte offset in 8KB tile (+c*4096)
  const char* Ag = (const char*)(A + (size_t)m0 * DM);
  const char* Bg = (const char*)(Bt + (size_t)n0 * DM);

  for (int k0 = 0; k0 < DM; k0 += 32) {
#pragma unroll
    for (int c = 0; c < 2; c++) {
      int o = ob + c * 4096;
      int row = o >> 6, colb = o & 63;
#ifdef HAVE_GLL
      GLL16(Ag + row * (DM * 2) + k0 * 2 + colb, (char*)lgA + w * 1024 + c * 4096);
      GLL16(Bg + row * (DM * 2) + k0 * 2 + colb, (char*)lgB + w * 1024 + c * 4096);
#else
      *(bf16x8*)((char*)lgA + o) = *(const bf16x8*)(Ag + row * (DM * 2) + k0 * 2 + colb);
      *(bf16x8*)((char*)lgB + o) = *(const bf16x8*)(Bg + row * (DM * 2) + k0 * 2 + colb);
#endif
    }
    __syncthreads();
    bf16x8 af[4], bfr[4];
#pragma unroll
    for (int m = 0; m < 4; m++)
      af[m] = *(const bf16x8*)&lgA[(wr * 64 + m * 16 + a15) * 32 + a4 * 8];
#pragma unroll
    for (int n = 0; n < 4; n++)
      bfr[n] = *(const bf16x8*)&lgB[(wc * 64 + n * 16 + a15) * 32 + a4 * 8];
#pragma unroll
    for (int m = 0; m < 4; m++)
#pragma unroll
      for (int n = 0; n < 4; n++)
        acc[m][n] = __builtin_amdgcn_mfma_f32_16x16x32_bf16(af[m], bfr[n], acc[m][n], 0, 0, 0);
    __syncthreads();
  }

#pragma unroll
  for (int m = 0; m < 4; m++) {
#pragma unroll
    for (int n = 0; n < 4; n++) {
      int gr0 = m0 + wr * 64 + m * 16 + a4 * 4;
      int col = n0 + wc * 64 + n * 16 + a15;
      float bv = bias[col];
      if constexpr (MODE == 2) {
        float* O = (float*)out;
#pragma unroll
        for (int j = 0; j < 4; j++)
          O[(size_t)(gr0 + j) * DM + col] = acc[m][n][j] + bv;
      } else if constexpr (MODE == 0) {
        uint16_t* O = (uint16_t*)out;
        int h = col >> 6, d = col & 63;
#pragma unroll
        for (int j = 0; j < 4; j++) {
          int gr = gr0 + j;
          int b = gr >> 11, s = gr & 2047;
          O[((size_t)(((b << 4) + h)) * SEQ + s) * HD + d] = f2bf(acc[m][n][j] + bv);
        }
      } else {
        uint16_t* O = (uint16_t*)out;
        int h = col >> 6, d = col & 63;
        int b = gr0 >> 11, s0 = gr0 & 2047;
        uint64_t pk = 0;
#pragma unroll
        for (int j = 0; j < 4; j++)
          pk |= (uint64_t)f2bf(acc[m][n][j] + bv) << (16 * j);
        *(uint64_t*)&O[((size_t)(((b << 4) + h)) * HD + d) * SEQ + s0] = pk;
      }
    }
  }
}

__global__ __launch_bounds__(256, 2) void gemm_qkv_kernel(
    const uint16_t* __restrict__ xb, const uint16_t* __restrict__ wtq,
    const uint16_t* __restrict__ wtk, const uint16_t* __restrict__ wtv,
    const float* __restrict__ bq, const float* __restrict__ bk,
    const float* __restrict__ bv, uint16_t* __restrict__ qo,
    uint16_t* __restrict__ ko, uint16_t* __restrict__ vto) {
  __shared__ __attribute__((aligned(16))) uint16_t lds[2 * 128 * 32];
  int z = blockIdx.z;
  if (z == 0)      gemm_body<0>(xb, wtq, bq, qo, lds);
  else if (z == 1) gemm_body<0>(xb, wtk, bk, ko, lds);
  else             gemm_body<1>(xb, wtv, bv, vto, lds);
}

__global__ __launch_bounds__(256, 2) void gemm_out_kernel(
    const uint16_t* __restrict__ ctx, const uint16_t* __restrict__ wto,
    const float* __restrict__ bo, float* __restrict__ out) {
  __shared__ __attribute__((aligned(16))) uint16_t lds[2 * 128 * 32];
  gemm_body<2>(ctx, wto, bo, out, lds);
}

// ---------------- attention: q[bh][s][64], k[bh][s][64], vt[bh][d][s] -> ctx[4096][1024] bf16
__global__ __launch_bounds__(256, 2) void attn_kernel(
    const uint16_t* __restrict__ qg, const uint16_t* __restrict__ kg,
    const uint16_t* __restrict__ vtg, uint16_t* __restrict__ ctx) {
  const int tid = threadIdx.x, w = tid >> 6, lane = tid & 63;
  const int a15 = lane & 15, a4 = lane >> 4;
  const int bh = blockIdx.y, qb = blockIdx.x;
  const int q0 = qb * 128 + w * 32;
  __shared__ __attribute__((aligned(16))) uint16_t Kl[64 * 72];
  __shared__ __attribute__((aligned(16))) uint16_t Vl[64 * 72];
  __shared__ __attribute__((aligned(16))) uint16_t Pl[4][32 * 72];
  const uint16_t* Qb = qg + (size_t)bh * SEQ * HD;
  const uint16_t* Kb = kg + (size_t)bh * SEQ * HD;
  const uint16_t* Vb = vtg + (size_t)bh * HD * SEQ;

  bf16x8 aq[2][2];
#pragma unroll
  for (int m = 0; m < 2; m++)
#pragma unroll
    for (int kk = 0; kk < 2; kk++)
      aq[m][kk] = *(const bf16x8*)&Qb[(q0 + m * 16 + a15) * HD + kk * 32 + a4 * 8];

  f32x4 zero = {0.0f, 0.0f, 0.0f, 0.0f};
  f32x4 acco[2][4];
  float mrun[2][4], lrun[2][4];
#pragma unroll
  for (int m = 0; m < 2; m++)
#pragma unroll
    for (int j = 0; j < 4; j++) { mrun[m][j] = -3.0e38f; lrun[m][j] = 0.0f; }
#pragma unroll
  for (int m = 0; m < 2; m++)
#pragma unroll
    for (int n = 0; n < 4; n++) acco[m][n] = zero;

  const float CS = 0.125f * 1.44269504088896f;  // log2(e)/sqrt(hd)

  for (int kb = 0; kb < SEQ; kb += 64) {
    __syncthreads();
#pragma unroll
    for (int i = 0; i < 2; i++) {
      int c2 = tid + i * 256;
      int r = c2 >> 3, off8 = (c2 & 7) * 8;
      *(bf16x8*)&Kl[r * 72 + off8] = *(const bf16x8*)&Kb[(size_t)(kb + r) * HD + off8];
      *(bf16x8*)&Vl[r * 72 + off8] = *(const bf16x8*)&Vb[(size_t)r * SEQ + kb + off8];
    }
    __syncthreads();

    // S = Q K^T (raw scores; 1/8 folded into exp constant)
    f32x4 s[2][4];
#pragma unroll
    for (int m = 0; m < 2; m++)
#pragma unroll
      for (int n = 0; n < 4; n++) s[m][n] = zero;
#pragma unroll
    for (int kk = 0; kk < 2; kk++) {
      bf16x8 bk4[4];
#pragma unroll
      for (int n = 0; n < 4; n++)
        bk4[n] = *(const bf16x8*)&Kl[(n * 16 + a15) * 72 + kk * 32 + a4 * 8];
#pragma unroll
      for (int m = 0; m < 2; m++)
#pragma unroll
        for (int n = 0; n < 4; n++)
          s[m][n] = __builtin_amdgcn_mfma_f32_16x16x32_bf16(aq[m][kk], bk4[n], s[m][n], 0, 0, 0);
    }

    // online softmax
#pragma unroll
    for (int m = 0; m < 2; m++) {
#pragma unroll
      for (int j = 0; j < 4; j++) {
        float t0 = fmaxf(fmaxf(s[m][0][j], s[m][1][j]), fmaxf(s[m][2][j], s[m][3][j]));
        t0 = fmaxf(t0, __shfl_xor(t0, 1));
        t0 = fmaxf(t0, __shfl_xor(t0, 2));
        t0 = fmaxf(t0, __shfl_xor(t0, 4));
        t0 = fmaxf(t0, __shfl_xor(t0, 8));
        float nm = fmaxf(mrun[m][j], t0);
        float f = EXP2F((mrun[m][j] - nm) * CS);
        mrun[m][j] = nm;
        lrun[m][j] *= f;
#pragma unroll
        for (int n = 0; n < 4; n++) acco[m][n][j] *= f;
        int row = m * 16 + a4 * 4 + j;
#pragma unroll
        for (int n = 0; n < 4; n++) {
          float p = EXP2F((s[m][n][j] - nm) * CS);
          lrun[m][j] += p;
          Pl[w][row * 72 + n * 16 + a15] = f2bf(p);
        }
      }
    }
    asm volatile("s_waitcnt lgkmcnt(0)" ::: "memory");

    // O += P V
#pragma unroll
    for (int kk = 0; kk < 2; kk++) {
      bf16x8 ap[2], bv4[4];
#pragma unroll
      for (int m = 0; m < 2; m++)
        ap[m] = *(const bf16x8*)&Pl[w][(m * 16 + a15) * 72 + kk * 32 + a4 * 8];
#pragma unroll
      for (int n = 0; n < 4; n++)
        bv4[n] = *(const bf16x8*)&Vl[(n * 16 + a15) * 72 + kk * 32 + a4 * 8];
#pragma unroll
      for (int m = 0; m < 2; m++)
#pragma unroll
        for (int n = 0; n < 4; n++)
          acco[m][n] = __builtin_amdgcn_mfma_f32_16x16x32_bf16(ap[m], bv4[n], acco[m][n], 0, 0, 0);
    }
  }

  int b = bh >> 4, h = bh & 15;
#pragma unroll
  for (int m = 0; m < 2; m++)
#pragma unroll
    for (int j = 0; j < 4; j++) {
      float l = lrun[m][j];
      l += __shfl_xor(l, 1);
      l += __shfl_xor(l, 2);
      l += __shfl_xor(l, 4);
      l += __shfl_xor(l, 8);
      float inv = 1.0f / l;
      int srow = q0 + m * 16 + a4 * 4 + j;
#pragma unroll
      for (int n = 0; n < 4; n++)
        ctx[(size_t)(b * SEQ + srow) * DM + h * HD + n * 16 + a15] =
            f2bf(acco[m][n][j] * inv);
    }
}

extern "C" void kernel_launch(void* const* d_in, const int* in_sizes, int n_in,
                              void* d_out, int out_size, void* d_ws, size_t ws_size,
                              hipStream_t stream) {
  const float* x  = (const float*)d_in[0];
  const float* Wq = (const float*)d_in[1];
  const float* bq = (const float*)d_in[2];
  const float* Wk = (const float*)d_in[3];
  const float* bk = (const float*)d_in[4];
  const float* Wv = (const float*)d_in[5];
  const float* bv = (const float*)d_in[6];
  const float* Wo = (const float*)d_in[7];
  const float* bo = (const float*)d_in[8];

  char* ws = (char*)d_ws;
  uint16_t* xb  = (uint16_t*)(ws);               // 8 MB  (aliased as ctx later)
  uint16_t* wtq = (uint16_t*)(ws + 8388608);     // 2 MB each
  uint16_t* wtk = (uint16_t*)(ws + 10485760);
  uint16_t* wtv = (uint16_t*)(ws + 12582912);
  uint16_t* wto = (uint16_t*)(ws + 14680064);
  uint16_t* qb  = (uint16_t*)(ws + 16777216);    // 8 MB
  uint16_t* kb  = (uint16_t*)(ws + 25165824);    // 8 MB
  uint16_t* vtb = (uint16_t*)(ws + 33554432);    // 8 MB
  uint16_t* ctx = xb;  // xb dead after gemm_qkv; reuse for ctx

  cvt_x_kernel<<<dim3(4096), dim3(256), 0, stream>>>(x, xb);
  twt_kernel<<<dim3(32, 32), dim3(32, 8), 0, stream>>>(Wq, wtq);
  twt_kernel<<<dim3(32, 32), dim3(32, 8), 0, stream>>>(Wk, wtk);
  twt_kernel<<<dim3(32, 32), dim3(32, 8), 0, stream>>>(Wv, wtv);
  twt_kernel<<<dim3(32, 32), dim3(32, 8), 0, stream>>>(Wo, wto);
  gemm_qkv_kernel<<<dim3(8, 32, 3), dim3(256), 0, stream>>>(
      xb, wtq, wtk, wtv, bq, bk, bv, qb, kb, vtb);
  attn_kernel<<<dim3(16, 32), dim3(256), 0, stream>>>(qb, kb, vtb, ctx);
  gemm_out_kernel<<<dim3(8, 32), dim3(256), 0, stream>>>(ctx, wto, bo, (float*)d_out);
}